// Round 1
// baseline (326.240 us; speedup 1.0000x reference)
//
#include <hip/hip_runtime.h>
#include <hip/hip_bf16.h>

#define B_  2
#define S_  2048
#define D_  1024
#define H_  16
#define HD_ 64
#define M_  (B_*S_)   // 4096

typedef __attribute__((ext_vector_type(4))) short s16x4;
typedef __attribute__((ext_vector_type(4))) float f32x4;

__device__ __forceinline__ unsigned short f2bf(float x) {
  union { float f; unsigned int u; } un; un.f = x;
  unsigned int r = un.u + 0x7fffu + ((un.u >> 16) & 1u);  // RNE
  return (unsigned short)(r >> 16);
}

__device__ __forceinline__ f32x4 fz4() { f32x4 z = {0.f, 0.f, 0.f, 0.f}; return z; }

// ---------------- fp32 -> bf16 convert (vectorized: float4 in, 4xbf16 out) ---------
__global__ __launch_bounds__(256) void cvt_kernel(const float4* __restrict__ src,
                                                  uint2* __restrict__ dst, int n4) {
  int i = blockIdx.x * 256 + threadIdx.x;
  int st = gridDim.x * 256;
  for (; i < n4; i += st) {
    float4 v = src[i];
    uint2 o;
    o.x = (unsigned)f2bf(v.x) | ((unsigned)f2bf(v.y) << 16);
    o.y = (unsigned)f2bf(v.z) | ((unsigned)f2bf(v.w) << 16);
    dst[i] = o;
  }
}

// ---------------- GEMM  C[M,N] = A[M,K] @ W[N,K]^T  (bf16 in, MODE0: bf16 head-layout out,
//                  MODE1: fp32 row-major out). Tile 128x128, BK=64, 4 waves. ----------
template<int MODE>
__global__ __launch_bounds__(256) void gemm_bt(const unsigned short* __restrict__ A,
                                               const unsigned short* __restrict__ W,
                                               unsigned short* __restrict__ obf,
                                               float* __restrict__ of,
                                               float scale) {
  __shared__ unsigned short As[128][72];   // +8 pad: stride 144B == 4 banks mod 32 -> 2-way
  __shared__ unsigned short Bs[128][72];
  const int tid  = threadIdx.x;
  const int lane = tid & 63;
  const int w    = tid >> 6;
  const int l15  = lane & 15, g = lane >> 4;
  const int m0 = blockIdx.x * 128;
  const int n0 = blockIdx.y * 128;
  const int wr = (w >> 1) * 64, wc = (w & 1) * 64;

  f32x4 acc[4][4];
  #pragma unroll
  for (int i = 0; i < 4; i++)
    #pragma unroll
    for (int j = 0; j < 4; j++) acc[i][j] = fz4();

  const int srow = tid >> 3;
  const int sch  = (tid & 7) * 8;

  for (int k0 = 0; k0 < D_; k0 += 64) {
    #pragma unroll
    for (int r = 0; r < 4; ++r) {
      int row = srow + r * 32;
      *(uint4*)&As[row][sch] = *(const uint4*)&A[(size_t)(m0 + row) * D_ + k0 + sch];
      *(uint4*)&Bs[row][sch] = *(const uint4*)&W[(size_t)(n0 + row) * D_ + k0 + sch];
    }
    __syncthreads();
    #pragma unroll
    for (int kk = 0; kk < 64; kk += 16) {
      s16x4 af[4], bf[4];
      #pragma unroll
      for (int mi = 0; mi < 4; mi++) af[mi] = *(const s16x4*)&As[wr + mi * 16 + l15][kk + 4 * g];
      #pragma unroll
      for (int ni = 0; ni < 4; ni++) bf[ni] = *(const s16x4*)&Bs[wc + ni * 16 + l15][kk + 4 * g];
      #pragma unroll
      for (int mi = 0; mi < 4; mi++)
        #pragma unroll
        for (int ni = 0; ni < 4; ni++)
          acc[mi][ni] = __builtin_amdgcn_mfma_f32_16x16x16bf16_1k(af[mi], bf[ni], acc[mi][ni], 0, 0, 0);
    }
    __syncthreads();
  }

  #pragma unroll
  for (int mi = 0; mi < 4; mi++)
    #pragma unroll
    for (int ni = 0; ni < 4; ni++)
      #pragma unroll
      for (int j = 0; j < 4; j++) {
        int r = m0 + wr + mi * 16 + 4 * g + j;   // output row (b*S+s)
        int c = n0 + wc + ni * 16 + l15;         // output col (h*HD+hd)
        float v = acc[mi][ni][j] * scale;
        if (MODE == 0) {
          int b = r >> 11, s = r & (S_ - 1), h = c >> 6, hd = c & 63;
          obf[(((size_t)(b * H_ + h)) * S_ + s) * HD_ + hd] = f2bf(v);
        } else {
          of[(size_t)r * D_ + c] = v;
        }
      }
}

// ---------------- Fused causal attention with "quiet softmax" (+1 denom) and
//                  PRE-MASK full-row max. Swapped QK^T: S^T = K @ Q^T so the
//                  S^T C-frags feed PV A-frags directly. 4 waves x 16 q-rows. ----------
__global__ __launch_bounds__(256) void attn_kernel(const unsigned short* __restrict__ Qh,
                                                   const unsigned short* __restrict__ Kh,
                                                   const unsigned short* __restrict__ Vh,
                                                   unsigned short* __restrict__ AO) {
  __shared__ unsigned short Ks[64][72];  // [key][hd], stride 144B -> 2-way
  __shared__ unsigned short Vt[64][88];  // [hd][key] transposed, stride 176B -> 2-way
  const int tid  = threadIdx.x;
  const int lane = tid & 63;
  const int w    = tid >> 6;
  const int l15  = lane & 15, g = lane >> 4;
  const int qt = blockIdx.x;     // q-tile (64 rows)
  const int bh = blockIdx.y;     // b*H + h
  const int q0 = qt * 64;
  const unsigned short* Qb = Qh + (size_t)bh * S_ * HD_;
  const unsigned short* Kb = Kh + (size_t)bh * S_ * HD_;
  const unsigned short* Vb = Vh + (size_t)bh * S_ * HD_;

  const int qrow = q0 + w * 16 + l15;  // this lane's q (column of S^T)
  s16x4 qf[4];
  #pragma unroll
  for (int kk = 0; kk < 4; kk++)
    qf[kk] = *(const s16x4*)&Qb[(size_t)qrow * HD_ + kk * 16 + 4 * g];

  float m = -INFINITY, l = 0.f;
  f32x4 outa[4];
  #pragma unroll
  for (int d = 0; d < 4; d++) outa[d] = fz4();

  const int krow = tid >> 3, kch = (tid & 7) * 8;
  const int vkey = tid & 63;

  for (int t = 0; t < 32; ++t) {   // ALL key blocks: max is pre-mask over full row
    const int k0 = t * 64;
    #pragma unroll
    for (int r = 0; r < 2; r++)
      *(uint4*)&Ks[krow + r * 32][kch] =
          *(const uint4*)&Kb[(size_t)(k0 + krow + r * 32) * HD_ + kch];
    if (t <= qt) {  // V only needed for causal blocks
      #pragma unroll
      for (int r = 0; r < 2; r++) {
        int hd0 = (w + r * 4) * 8;
        uint4 vv = *(const uint4*)&Vb[(size_t)(k0 + vkey) * HD_ + hd0];
        unsigned int u[4] = {vv.x, vv.y, vv.z, vv.w};
        #pragma unroll
        for (int c2 = 0; c2 < 4; c2++) {
          Vt[hd0 + 2 * c2    ][vkey] = (unsigned short)(u[c2] & 0xffffu);
          Vt[hd0 + 2 * c2 + 1][vkey] = (unsigned short)(u[c2] >> 16);
        }
      }
    }
    __syncthreads();

    // S^T(64key x 16q) per wave: 4 key-subtiles
    f32x4 sf[4];
    #pragma unroll
    for (int kt = 0; kt < 4; kt++) sf[kt] = fz4();
    #pragma unroll
    for (int kt = 0; kt < 4; kt++)
      #pragma unroll
      for (int kk = 0; kk < 4; kk++) {
        s16x4 kf = *(const s16x4*)&Ks[kt * 16 + l15][kk * 16 + 4 * g];
        sf[kt] = __builtin_amdgcn_mfma_f32_16x16x16bf16_1k(kf, qf[kk], sf[kt], 0, 0, 0);
      }

    // pre-mask block max for this lane's q, then across the 4 lane-groups
    float bm = -INFINITY;
    #pragma unroll
    for (int kt = 0; kt < 4; kt++)
      #pragma unroll
      for (int j = 0; j < 4; j++) bm = fmaxf(bm, sf[kt][j]);
    bm = fmaxf(bm, __shfl_xor(bm, 16));
    bm = fmaxf(bm, __shfl_xor(bm, 32));
    float mn  = fmaxf(m, bm);
    float fsc = __expf(m - mn);   // m = -inf initially -> 0
    m = mn;
    l *= fsc;
    float frow[4];
    #pragma unroll
    for (int j = 0; j < 4; j++) frow[j] = __shfl(fsc, 4 * g + j);
    #pragma unroll
    for (int d = 0; d < 4; d++)
      #pragma unroll
      for (int j = 0; j < 4; j++) outa[d][j] *= frow[j];

    if (t <= qt) {
      s16x4 pf[4];
      float rs = 0.f;
      #pragma unroll
      for (int kt = 0; kt < 4; kt++)
        #pragma unroll
        for (int j = 0; j < 4; j++) {
          int keyg = k0 + kt * 16 + 4 * g + j;
          float e = (keyg <= qrow) ? __expf(sf[kt][j] - m) : 0.f;
          rs += e;
          pf[kt][j] = (short)f2bf(e);
        }
      rs += __shfl_xor(rs, 16);
      rs += __shfl_xor(rs, 32);
      l += rs;
      #pragma unroll
      for (int d = 0; d < 4; d++)
        #pragma unroll
        for (int kt = 0; kt < 4; kt++) {
          s16x4 vf = *(const s16x4*)&Vt[d * 16 + l15][kt * 16 + 4 * g];
          outa[d] = __builtin_amdgcn_mfma_f32_16x16x16bf16_1k(pf[kt], vf, outa[d], 0, 0, 0);
        }
    }
    __syncthreads();
  }

  float inv = 1.f / (l + 1.f);   // quiet softmax +1
  float invr[4];
  #pragma unroll
  for (int j = 0; j < 4; j++) invr[j] = __shfl(inv, 4 * g + j);
  const int b = bh >> 4, h = bh & 15;
  #pragma unroll
  for (int d = 0; d < 4; d++)
    #pragma unroll
    for (int j = 0; j < 4; j++) {
      int row = q0 + w * 16 + 4 * g + j;
      int col = h * 64 + d * 16 + l15;
      AO[(size_t)(b * S_ + row) * D_ + col] = f2bf(outa[d][j] * invr[j]);
    }
}

extern "C" void kernel_launch(void* const* d_in, const int* in_sizes, int n_in,
                              void* d_out, int out_size, void* d_ws, size_t ws_size,
                              hipStream_t stream) {
  const float* q  = (const float*)d_in[0];
  const float* k  = (const float*)d_in[1];
  const float* v  = (const float*)d_in[2];
  const float* Wq = (const float*)d_in[3];
  const float* Wk = (const float*)d_in[4];
  const float* Wv = (const float*)d_in[5];
  const float* Wo = (const float*)d_in[6];

  unsigned short* ws  = (unsigned short*)d_ws;
  unsigned short* qb  = ws;                    // 4096x1024 bf16
  unsigned short* kb  = qb  + 4194304;
  unsigned short* vb  = kb  + 4194304;
  unsigned short* Wqb = vb  + 4194304;         // 1024x1024 bf16 x4
  unsigned short* Wkb = Wqb + 1048576;
  unsigned short* Wvb = Wkb + 1048576;
  unsigned short* Wob = Wvb + 1048576;
  unsigned short* Qh  = Wob + 1048576;         // (b,h,s,hd) bf16 x3
  unsigned short* Kh  = Qh  + 4194304;
  unsigned short* Vh  = Kh  + 4194304;
  unsigned short* AO  = Vh  + 4194304;         // attn out, (b*s, h*hd) bf16

  cvt_kernel<<<2048, 256, 0, stream>>>((const float4*)q,  (uint2*)qb,  1048576);
  cvt_kernel<<<2048, 256, 0, stream>>>((const float4*)k,  (uint2*)kb,  1048576);
  cvt_kernel<<<2048, 256, 0, stream>>>((const float4*)v,  (uint2*)vb,  1048576);
  cvt_kernel<<<1024, 256, 0, stream>>>((const float4*)Wq, (uint2*)Wqb, 262144);
  cvt_kernel<<<1024, 256, 0, stream>>>((const float4*)Wk, (uint2*)Wkb, 262144);
  cvt_kernel<<<1024, 256, 0, stream>>>((const float4*)Wv, (uint2*)Wvb, 262144);
  cvt_kernel<<<1024, 256, 0, stream>>>((const float4*)Wo, (uint2*)Wob, 262144);

  dim3 gg(M_ / 128, D_ / 128);  // 32 x 8
  // Q projection folds the 1/sqrt(HD)=0.125 score scale
  gemm_bt<0><<<gg, 256, 0, stream>>>(qb, Wqb, Qh, nullptr, 0.125f);
  gemm_bt<0><<<gg, 256, 0, stream>>>(kb, Wkb, Kh, nullptr, 1.0f);
  gemm_bt<0><<<gg, 256, 0, stream>>>(vb, Wvb, Vh, nullptr, 1.0f);

  attn_kernel<<<dim3(S_ / 64, B_ * H_), 256, 0, stream>>>(Qh, Kh, Vh, AO);

  gemm_bt<1><<<gg, 256, 0, stream>>>(AO, Wob, nullptr, (float*)d_out, 1.0f);
}

// Round 2
// 278.816 us; speedup vs baseline: 1.1701x; 1.1701x over previous
//
#include <hip/hip_runtime.h>
#include <hip/hip_bf16.h>

#define B_  2
#define S_  2048
#define D_  1024
#define H_  16
#define HD_ 64
#define M_  (B_*S_)   // 4096

typedef __attribute__((ext_vector_type(4))) short s16x4;
typedef __attribute__((ext_vector_type(8))) short s16x8;
typedef __attribute__((ext_vector_type(4))) float f32x4;
typedef __attribute__((ext_vector_type(8))) __bf16 bf16x8;

__device__ __forceinline__ unsigned short f2bf(float x) {
  union { float f; unsigned int u; } un; un.f = x;
  unsigned int r = un.u + 0x7fffu + ((un.u >> 16) & 1u);  // RNE
  return (unsigned short)(r >> 16);
}

__device__ __forceinline__ f32x4 fz4() { f32x4 z = {0.f, 0.f, 0.f, 0.f}; return z; }

__device__ __forceinline__ f32x4 mfma32(s16x8 a, s16x8 b, f32x4 c) {
  return __builtin_amdgcn_mfma_f32_16x16x32_bf16(
      __builtin_bit_cast(bf16x8, a), __builtin_bit_cast(bf16x8, b), c, 0, 0, 0);
}

// async global->LDS, 16B per lane. Dest is wave-uniform base + lane*16 (HW adds lane).
__device__ __forceinline__ void gload16(void* lds_base, const void* gsrc) {
  __builtin_amdgcn_global_load_lds(
      (const __attribute__((address_space(1))) unsigned int*)gsrc,
      (__attribute__((address_space(3))) unsigned int*)lds_base, 16, 0, 0);
}

// ---------------- fp32 -> bf16 convert, ALL 7 tensors in one launch ----------------
__global__ __launch_bounds__(256) void cvt_all(const float4* __restrict__ q,
                                               const float4* __restrict__ k,
                                               const float4* __restrict__ v,
                                               const float4* __restrict__ wq,
                                               const float4* __restrict__ wk,
                                               const float4* __restrict__ wv,
                                               const float4* __restrict__ wo,
                                               uint2* __restrict__ oq, uint2* __restrict__ ok,
                                               uint2* __restrict__ ov, uint2* __restrict__ owq,
                                               uint2* __restrict__ owk, uint2* __restrict__ owv,
                                               uint2* __restrict__ owo) {
  int i = blockIdx.x * 256 + threadIdx.x;
  int st = gridDim.x * 256;
  for (; i < 4194304; i += st) {
    const float4* s; uint2* d; int off;
    if (i < 3145728) {
      int t = i >> 20; off = i & 1048575;
      s = (t == 0) ? q : (t == 1 ? k : v);
      d = (t == 0) ? oq : (t == 1 ? ok : ov);
    } else {
      int j = i - 3145728;
      int t = j >> 18; off = j & 262143;
      s = (t == 0) ? wq : (t == 1 ? wk : (t == 2 ? wv : wo));
      d = (t == 0) ? owq : (t == 1 ? owk : (t == 2 ? owv : owo));
    }
    float4 x = s[off];
    uint2 o;
    o.x = (unsigned)f2bf(x.x) | ((unsigned)f2bf(x.y) << 16);
    o.y = (unsigned)f2bf(x.z) | ((unsigned)f2bf(x.w) << 16);
    d[off] = o;
  }
}

// ---------------- GEMM  C[M,N] = A[M,K] @ W[N,K]^T   (m97 structure)
//   128x128 tile, BK=64, 4 waves, global_load_lds dwordx4 staging with
//   source-side 16B-slot XOR swizzle, ds_read_b128 frags, 16x16x32 MFMA.
template<int MODE>
__global__ __launch_bounds__(256) void gemm_bt(const unsigned short* __restrict__ A,
                                               const unsigned short* __restrict__ W,
                                               unsigned short* __restrict__ obf,
                                               float* __restrict__ of,
                                               float scale) {
  __shared__ unsigned short As[128 * 64];   // [row][64] linear, content chunk-swizzled
  __shared__ unsigned short Bs[128 * 64];
  const int tid  = threadIdx.x;
  const int lane = tid & 63;
  const int w    = tid >> 6;
  const int l15  = lane & 15, g = lane >> 4;

  // XCD swizzle: 256 blocks = 8 XCD chunks of 32; XCD x owns N-column by=x.
  int swz = (blockIdx.x & 7) * 32 + (blockIdx.x >> 3);
  const int m0 = (swz & 31) * 128;
  const int n0 = (swz >> 5) * 128;
  const int wr = (w >> 1) * 64, wc = (w & 1) * 64;

  f32x4 acc[4][4];
  #pragma unroll
  for (int i = 0; i < 4; i++)
    #pragma unroll
    for (int j = 0; j < 4; j++) acc[i][j] = fz4();

  // staging geometry: slot s = i*256 + w*64 + lane  ->  row = s>>3, chunk c = lane&7.
  // LDS[row][c] holds source chunk (c ^ (row&7))  (T2 swizzle, applied on the source).
  const int srow = w * 8 + (lane >> 3);                      // + i*32
  const int scol = ((lane & 7) ^ ((lane >> 3) & 7)) * 8;     // pre-swizzled source chunk

  for (int k0 = 0; k0 < D_; k0 += 64) {
    #pragma unroll
    for (int i = 0; i < 4; i++) {
      int row = i * 32 + srow;
      gload16(&As[(i * 256 + w * 64) * 8], &A[(size_t)(m0 + row) * D_ + k0 + scol]);
      gload16(&Bs[(i * 256 + w * 64) * 8], &W[(size_t)(n0 + row) * D_ + k0 + scol]);
    }
    __syncthreads();
    #pragma unroll
    for (int kk = 0; kk < 2; kk++) {
      s16x8 af[4], bfr[4];
      #pragma unroll
      for (int mi = 0; mi < 4; mi++)
        af[mi] = *(const s16x8*)&As[(wr + mi * 16 + l15) * 64 + (((kk * 4 + g) ^ (l15 & 7)) * 8)];
      #pragma unroll
      for (int ni = 0; ni < 4; ni++)
        bfr[ni] = *(const s16x8*)&Bs[(wc + ni * 16 + l15) * 64 + (((kk * 4 + g) ^ (l15 & 7)) * 8)];
      #pragma unroll
      for (int mi = 0; mi < 4; mi++)
        #pragma unroll
        for (int ni = 0; ni < 4; ni++)
          acc[mi][ni] = mfma32(af[mi], bfr[ni], acc[mi][ni]);
    }
    __syncthreads();
  }

  #pragma unroll
  for (int mi = 0; mi < 4; mi++)
    #pragma unroll
    for (int ni = 0; ni < 4; ni++)
      #pragma unroll
      for (int j = 0; j < 4; j++) {
        int r = m0 + wr + mi * 16 + 4 * g + j;   // output row (b*S+s)
        int c = n0 + wc + ni * 16 + l15;         // output col (h*HD+hd)
        float v = acc[mi][ni][j] * scale;
        if (MODE == 0) {
          int b = r >> 11, s = r & (S_ - 1), h = c >> 6, hd = c & 63;
          obf[(((size_t)(b * H_ + h)) * S_ + s) * HD_ + hd] = f2bf(v);
        } else {
          of[(size_t)r * D_ + c] = v;
        }
      }
}

// ---------------- Fused causal attention, quiet softmax (+1), PRE-MASK full-row max.
//   Swapped QK^T (S^T = K @ Q^T), 16x16x32 MFMA, K staged via global_load_lds
//   (swizzled source), V transposed in LDS with conflict-free pad 76.
__global__ __launch_bounds__(256) void attn_kernel(const unsigned short* __restrict__ Qh,
                                                   const unsigned short* __restrict__ Kh,
                                                   const unsigned short* __restrict__ Vh,
                                                   unsigned short* __restrict__ AO) {
  __shared__ unsigned short Ks[64 * 64];   // [key][64] linear, chunk-swizzled content
  __shared__ unsigned short Vt[64 * 76];   // [hd][key], pad 76: uniform bank load
  const int tid  = threadIdx.x;
  const int lane = tid & 63;
  const int w    = tid >> 6;
  const int l15  = lane & 15, g = lane >> 4;

  // XCD swizzle over flat grid (1024 blocks): XCD x gets 128 contiguous = 4 bh values.
  int swz = (blockIdx.x & 7) * 128 + (blockIdx.x >> 3);
  const int qt = swz & 31;      // q-tile (64 rows)
  const int bh = swz >> 5;      // b*H + h
  const int q0 = qt * 64;
  const unsigned short* Qb = Qh + (size_t)bh * S_ * HD_;
  const unsigned short* Kb = Kh + (size_t)bh * S_ * HD_;
  const unsigned short* Vb = Vh + (size_t)bh * S_ * HD_;

  const int qrow = q0 + w * 16 + l15;  // this lane's q (column of S^T)
  s16x8 qf[2];
  #pragma unroll
  for (int kk = 0; kk < 2; kk++)
    qf[kk] = *(const s16x8*)&Qb[(size_t)qrow * HD_ + kk * 32 + 8 * g];

  float m = -INFINITY, l = 0.f;
  f32x4 outa[4];
  #pragma unroll
  for (int d = 0; d < 4; d++) outa[d] = fz4();

  const int srow = w * 8 + (lane >> 3);                   // + i*32
  const int scol = ((lane & 7) ^ ((lane >> 3) & 7)) * 8;  // pre-swizzled source chunk
  const int vkey = tid & 63;

  for (int t = 0; t < 32; ++t) {   // ALL key blocks: max is pre-mask over the full row
    const int k0 = t * 64;
    #pragma unroll
    for (int i = 0; i < 2; i++)
      gload16(&Ks[(i * 256 + w * 64) * 8],
              &Kb[(size_t)(k0 + i * 32 + srow) * HD_ + scol]);
    if (t <= qt) {  // V only needed for causal blocks
      #pragma unroll
      for (int r = 0; r < 2; r++) {
        int hd0 = (w + r * 4) * 8;
        uint4 vv = *(const uint4*)&Vb[(size_t)(k0 + vkey) * HD_ + hd0];
        unsigned int u[4] = {vv.x, vv.y, vv.z, vv.w};
        #pragma unroll
        for (int c2 = 0; c2 < 4; c2++) {
          Vt[(hd0 + 2 * c2    ) * 76 + vkey] = (unsigned short)(u[c2] & 0xffffu);
          Vt[(hd0 + 2 * c2 + 1) * 76 + vkey] = (unsigned short)(u[c2] >> 16);
        }
      }
    }
    __syncthreads();

    // S^T(64key x 16q) per wave: 4 key-subtiles x 2 K-halves (hd)
    f32x4 sf[4];
    #pragma unroll
    for (int kt = 0; kt < 4; kt++) sf[kt] = fz4();
    __builtin_amdgcn_s_setprio(1);
    #pragma unroll
    for (int kt = 0; kt < 4; kt++)
      #pragma unroll
      for (int kk = 0; kk < 2; kk++) {
        s16x8 kf = *(const s16x8*)&Ks[(kt * 16 + l15) * 64 + (((kk * 4 + g) ^ (l15 & 7)) * 8)];
        sf[kt] = mfma32(kf, qf[kk], sf[kt]);
      }
    __builtin_amdgcn_s_setprio(0);

    // pre-mask block max for this lane's q, then across the 4 lane-groups
    float bm = -INFINITY;
    #pragma unroll
    for (int kt = 0; kt < 4; kt++)
      #pragma unroll
      for (int j = 0; j < 4; j++) bm = fmaxf(bm, sf[kt][j]);
    bm = fmaxf(bm, __shfl_xor(bm, 16));
    bm = fmaxf(bm, __shfl_xor(bm, 32));
    float mn  = fmaxf(m, bm);
    float fsc = __expf(m - mn);   // m = -inf initially -> 0
    m = mn;
    l *= fsc;
    float frow[4];
    #pragma unroll
    for (int j = 0; j < 4; j++) frow[j] = __shfl(fsc, 4 * g + j);
    #pragma unroll
    for (int d = 0; d < 4; d++)
      #pragma unroll
      for (int j = 0; j < 4; j++) outa[d][j] *= frow[j];

    if (t <= qt) {
      s16x8 pfs[2];
      float rs = 0.f;
      #pragma unroll
      for (int kt2 = 0; kt2 < 2; kt2++) {
        #pragma unroll
        for (int j = 0; j < 4; j++) {
          int keyg = k0 + kt2 * 32 + 4 * g + j;
          float e = (keyg <= qrow) ? __expf(sf[2 * kt2][j] - m) : 0.f;
          rs += e;
          pfs[kt2][j] = (short)f2bf(e);
          float e2 = (keyg + 16 <= qrow) ? __expf(sf[2 * kt2 + 1][j] - m) : 0.f;
          rs += e2;
          pfs[kt2][4 + j] = (short)f2bf(e2);
        }
      }
      rs += __shfl_xor(rs, 16);
      rs += __shfl_xor(rs, 32);
      l += rs;
      __builtin_amdgcn_s_setprio(1);
      #pragma unroll
      for (int d = 0; d < 4; d++)
        #pragma unroll
        for (int kt2 = 0; kt2 < 2; kt2++) {
          s16x4 vlo = *(const s16x4*)&Vt[(d * 16 + l15) * 76 + kt2 * 32 + 4 * g];
          s16x4 vhi = *(const s16x4*)&Vt[(d * 16 + l15) * 76 + kt2 * 32 + 16 + 4 * g];
          s16x8 vv = {vlo[0], vlo[1], vlo[2], vlo[3], vhi[0], vhi[1], vhi[2], vhi[3]};
          outa[d] = mfma32(pfs[kt2], vv, outa[d]);
        }
      __builtin_amdgcn_s_setprio(0);
    }
    __syncthreads();
  }

  float inv = 1.f / (l + 1.f);   // quiet softmax +1
  float invr[4];
  #pragma unroll
  for (int j = 0; j < 4; j++) invr[j] = __shfl(inv, 4 * g + j);
  const int b = bh >> 4, h = bh & 15;
  #pragma unroll
  for (int d = 0; d < 4; d++)
    #pragma unroll
    for (int j = 0; j < 4; j++) {
      int row = q0 + w * 16 + 4 * g + j;
      int col = h * 64 + d * 16 + l15;
      AO[(size_t)(b * S_ + row) * D_ + col] = f2bf(outa[d][j] * invr[j]);
    }
}

extern "C" void kernel_launch(void* const* d_in, const int* in_sizes, int n_in,
                              void* d_out, int out_size, void* d_ws, size_t ws_size,
                              hipStream_t stream) {
  const float* q  = (const float*)d_in[0];
  const float* k  = (const float*)d_in[1];
  const float* v  = (const float*)d_in[2];
  const float* Wq = (const float*)d_in[3];
  const float* Wk = (const float*)d_in[4];
  const float* Wv = (const float*)d_in[5];
  const float* Wo = (const float*)d_in[6];

  unsigned short* ws  = (unsigned short*)d_ws;
  unsigned short* qb  = ws;                    // 4096x1024 bf16
  unsigned short* kb  = qb  + 4194304;
  unsigned short* vb  = kb  + 4194304;
  unsigned short* Wqb = vb  + 4194304;         // 1024x1024 bf16 x4
  unsigned short* Wkb = Wqb + 1048576;
  unsigned short* Wvb = Wkb + 1048576;
  unsigned short* Wob = Wvb + 1048576;
  unsigned short* Qh  = Wob + 1048576;         // (b,h,s,hd) bf16 x3
  unsigned short* Kh  = Qh  + 4194304;
  unsigned short* Vh  = Kh  + 4194304;
  unsigned short* AO  = Vh  + 4194304;         // attn out, (b*s, h*hd) bf16

  cvt_all<<<2048, 256, 0, stream>>>((const float4*)q, (const float4*)k, (const float4*)v,
                                    (const float4*)Wq, (const float4*)Wk, (const float4*)Wv,
                                    (const float4*)Wo,
                                    (uint2*)qb, (uint2*)kb, (uint2*)vb, (uint2*)Wqb,
                                    (uint2*)Wkb, (uint2*)Wvb, (uint2*)Wob);

  // Q projection folds the 1/sqrt(HD)=0.125 score scale
  gemm_bt<0><<<256, 256, 0, stream>>>(qb, Wqb, Qh, nullptr, 0.125f);
  gemm_bt<0><<<256, 256, 0, stream>>>(kb, Wkb, Kh, nullptr, 1.0f);
  gemm_bt<0><<<256, 256, 0, stream>>>(vb, Wvb, Vh, nullptr, 1.0f);

  attn_kernel<<<1024, 256, 0, stream>>>(Qh, Kh, Vh, AO);

  gemm_bt<1><<<256, 256, 0, stream>>>(AO, Wob, nullptr, (float*)d_out, 1.0f);
}

// Round 4
// 252.710 us; speedup vs baseline: 1.2910x; 1.1033x over previous
//
#include <hip/hip_runtime.h>
#include <hip/hip_bf16.h>

#define B_  2
#define S_  2048
#define D_  1024
#define H_  16
#define HD_ 64

typedef __attribute__((ext_vector_type(4))) short s16x4;
typedef __attribute__((ext_vector_type(8))) short s16x8;
typedef __attribute__((ext_vector_type(4))) float f32x4;
typedef __attribute__((ext_vector_type(8))) __bf16 bf16x8;

__device__ __forceinline__ unsigned short f2bf(float x) {
  union { float f; unsigned int u; } un; un.f = x;
  unsigned int r = un.u + 0x7fffu + ((un.u >> 16) & 1u);  // RNE
  return (unsigned short)(r >> 16);
}

__device__ __forceinline__ f32x4 fz4() { f32x4 z = {0.f, 0.f, 0.f, 0.f}; return z; }

__device__ __forceinline__ f32x4 mfma32(s16x8 a, s16x8 b, f32x4 c) {
  return __builtin_amdgcn_mfma_f32_16x16x32_bf16(
      __builtin_bit_cast(bf16x8, a), __builtin_bit_cast(bf16x8, b), c, 0, 0, 0);
}

// async global->LDS, 16B per lane. Dest is wave-uniform base + lane*16 (HW adds lane).
__device__ __forceinline__ void gload16(void* lds_base, const void* gsrc) {
  __builtin_amdgcn_global_load_lds(
      (const __attribute__((address_space(1))) unsigned int*)gsrc,
      (__attribute__((address_space(3))) unsigned int*)lds_base, 16, 0, 0);
}

// ---------------- fp32 -> bf16 convert, ALL 7 tensors in one launch ----------------
__global__ __launch_bounds__(256) void cvt_all(const float4* __restrict__ q,
                                               const float4* __restrict__ k,
                                               const float4* __restrict__ v,
                                               const float4* __restrict__ wq,
                                               const float4* __restrict__ wk,
                                               const float4* __restrict__ wv,
                                               const float4* __restrict__ wo,
                                               uint2* __restrict__ oq, uint2* __restrict__ ok,
                                               uint2* __restrict__ ov, uint2* __restrict__ owq,
                                               uint2* __restrict__ owk, uint2* __restrict__ owv,
                                               uint2* __restrict__ owo) {
  int i = blockIdx.x * 256 + threadIdx.x;
  int st = gridDim.x * 256;
  for (; i < 4194304; i += st) {
    const float4* s; uint2* d; int off;
    if (i < 3145728) {
      int t = i >> 20; off = i & 1048575;
      s = (t == 0) ? q : (t == 1 ? k : v);
      d = (t == 0) ? oq : (t == 1 ? ok : ov);
    } else {
      int j = i - 3145728;
      int t = j >> 18; off = j & 262143;
      s = (t == 0) ? wq : (t == 1 ? wk : (t == 2 ? wv : wo));
      d = (t == 0) ? owq : (t == 1 ? owk : (t == 2 ? owv : owo));
    }
    float4 x = s[off];
    uint2 o;
    o.x = (unsigned)f2bf(x.x) | ((unsigned)f2bf(x.y) << 16);
    o.y = (unsigned)f2bf(x.z) | ((unsigned)f2bf(x.w) << 16);
    d[off] = o;
  }
}

// ---------------- GEMM  C[M,N] = A[M,K] @ W[N,K]^T
//   Tile BM x 128, BK=32, double-buffered LDS, 2-phase schedule (stage next
//   tile before compute, one barrier/iter). NG=3 fuses the QKV projections
//   into one launch (768 blocks = 3 panels/XCD) for 3-blocks/CU residency.
template<int BM, int MODE, int NG>
__global__ __launch_bounds__(256) void gemm_bt(
    const unsigned short* __restrict__ A0, const unsigned short* __restrict__ A1,
    const unsigned short* __restrict__ A2,
    const unsigned short* __restrict__ W0, const unsigned short* __restrict__ W1,
    const unsigned short* __restrict__ W2,
    unsigned short* __restrict__ ob0, unsigned short* __restrict__ ob1,
    unsigned short* __restrict__ ob2, float* __restrict__ of) {
  __shared__ unsigned short As[2][BM * 32];
  __shared__ unsigned short Bs[2][128 * 32];
  const int tid  = threadIdx.x;
  const int lane = tid & 63;
  const int w    = tid >> 6;
  const int l15  = lane & 15, g = lane >> 4;

  int m0, n0;
  const unsigned short *A, *W;
  unsigned short* obf;
  float scale = 1.0f;
  if (NG == 3) {
    int swz = ((int)blockIdx.x & 7) * 96 + ((int)blockIdx.x >> 3);
    int p  = swz >> 5;          // panel 0..23 (3 consecutive per XCD)
    int gi = p >> 3;            // which gemm
    n0 = (p & 7) * 128;
    m0 = (swz & 31) * 128;
    A   = gi == 0 ? A0 : (gi == 1 ? A1 : A2);
    W   = gi == 0 ? W0 : (gi == 1 ? W1 : W2);
    obf = gi == 0 ? ob0 : (gi == 1 ? ob1 : ob2);
    scale = (gi == 0) ? 0.125f : 1.0f;   // fold 1/sqrt(HD) into Q
  } else {
    int swz = ((int)blockIdx.x & 7) * 64 + ((int)blockIdx.x >> 3);
    m0 = (swz & 63) * BM;
    n0 = (swz >> 6) * 128;
    A = A0; W = W0; obf = ob0;
  }

  constexpr int MI  = (BM == 128) ? 4 : 2;
  const int wr = (w >> 1) * (MI * 16);
  const int wc = (w & 1) * 64;

  f32x4 acc[MI][4];
  #pragma unroll
  for (int i = 0; i < MI; i++)
    #pragma unroll
    for (int j = 0; j < 4; j++) acc[i][j] = fz4();

  // staging: rows are 32 shorts (64B) = 4 16B-chunks; T2 swizzle chunk^(row&3)
  // applied on the SOURCE address (LDS dest stays linear: gload_lds rule #21).
  const int srow = w * 16 + (lane >> 2);
  const int scol = ((lane & 3) ^ ((lane >> 2) & 3)) * 8;

  #define STAGE(buf, k0)                                                          \
    {                                                                             \
      _Pragma("unroll")                                                           \
      for (int i = 0; i < BM / 64; i++)                                           \
        gload16(&As[buf][(i * 64 + w * 16) * 32],                                 \
                &A[(size_t)(m0 + i * 64 + srow) * D_ + (k0) + scol]);             \
      _Pragma("unroll")                                                           \
      for (int i = 0; i < 2; i++)                                                 \
        gload16(&Bs[buf][(i * 64 + w * 16) * 32],                                 \
                &W[(size_t)(n0 + i * 64 + srow) * D_ + (k0) + scol]);             \
    }

  STAGE(0, 0);
  __syncthreads();
  int buf = 0;
  for (int t = 0; t < 32; ++t) {
    if (t < 31) STAGE(buf ^ 1, (t + 1) * 32);
    s16x8 af[MI], bfr[4];
    #pragma unroll
    for (int mi = 0; mi < MI; mi++)
      af[mi] = *(const s16x8*)&As[buf][(wr + mi * 16 + l15) * 32 + ((g ^ (l15 & 3)) * 8)];
    #pragma unroll
    for (int ni = 0; ni < 4; ni++)
      bfr[ni] = *(const s16x8*)&Bs[buf][(wc + ni * 16 + l15) * 32 + ((g ^ (l15 & 3)) * 8)];
    __builtin_amdgcn_s_setprio(1);
    #pragma unroll
    for (int mi = 0; mi < MI; mi++)
      #pragma unroll
      for (int ni = 0; ni < 4; ni++)
        acc[mi][ni] = mfma32(af[mi], bfr[ni], acc[mi][ni]);
    __builtin_amdgcn_s_setprio(0);
    __syncthreads();
    buf ^= 1;
  }
  #undef STAGE

  #pragma unroll
  for (int mi = 0; mi < MI; mi++)
    #pragma unroll
    for (int ni = 0; ni < 4; ni++)
      #pragma unroll
      for (int j = 0; j < 4; j++) {
        int r = m0 + wr + mi * 16 + 4 * g + j;   // output row (b*S+s)
        int c = n0 + wc + ni * 16 + l15;         // output col (h*HD+hd)
        float v = acc[mi][ni][j] * scale;
        if (MODE == 0) {
          int b = r >> 11, s = r & (S_ - 1), h = c >> 6, hd = c & 63;
          obf[(((size_t)(b * H_ + h)) * S_ + s) * HD_ + hd] = f2bf(v);
        } else {
          of[(size_t)r * D_ + c] = v;
        }
      }
}

// ---------------- Fused causal attention, quiet softmax (+1), PRE-MASK full-row max.
//   Swapped QK^T (S^T = K @ Q^T), 16x16x32 MFMA. Double-buffered K (global_load_lds,
//   swizzled source) and V (reg-staged transpose, write-late). Exact defer-max.
__global__ __launch_bounds__(256) void attn_kernel(const unsigned short* __restrict__ Qh,
                                                   const unsigned short* __restrict__ Kh,
                                                   const unsigned short* __restrict__ Vh,
                                                   unsigned short* __restrict__ AO) {
  __shared__ unsigned short Ks[2][64 * 64];   // [key][64] linear, chunk-swizzled content
  __shared__ unsigned short Vt[2][64 * 76];   // [hd][key], pad 76: conflict-free
  const int tid  = threadIdx.x;
  const int lane = tid & 63;
  const int w    = tid >> 6;
  const int l15  = lane & 15, g = lane >> 4;

  int swz = (blockIdx.x & 7) * 128 + (blockIdx.x >> 3);
  const int qt = swz & 31;      // q-tile (64 rows)
  const int bh = swz >> 5;      // b*H + h
  const int q0 = qt * 64;
  const unsigned short* Qb = Qh + (size_t)bh * S_ * HD_;
  const unsigned short* Kb = Kh + (size_t)bh * S_ * HD_;
  const unsigned short* Vb = Vh + (size_t)bh * S_ * HD_;

  const int qrow = q0 + w * 16 + l15;  // this lane's q (column of S^T)
  s16x8 qf[2];
  #pragma unroll
  for (int kk = 0; kk < 2; kk++)
    qf[kk] = *(const s16x8*)&Qb[(size_t)qrow * HD_ + kk * 32 + 8 * g];

  float m = -INFINITY, l = 0.f;
  f32x4 outa[4];
  #pragma unroll
  for (int d = 0; d < 4; d++) outa[d] = fz4();

  const int srow = w * 8 + (lane >> 3);
  const int scol = ((lane & 7) ^ ((lane >> 3) & 7)) * 8;
  const int vkey = tid & 63;

  #define STAGE_K(kblk, b)                                                        \
    {                                                                             \
      _Pragma("unroll")                                                           \
      for (int i = 0; i < 2; i++)                                                 \
        gload16(&Ks[b][(i * 256 + w * 64) * 8],                                   \
                &Kb[(size_t)((kblk) * 64 + i * 32 + srow) * HD_ + scol]);         \
    }
  #define LOAD_V(kblk, vr)                                                        \
    {                                                                             \
      _Pragma("unroll")                                                           \
      for (int r = 0; r < 2; r++)                                                 \
        vr[r] = *(const uint4*)&Vb[(size_t)((kblk) * 64 + vkey) * HD_ + (w + r * 4) * 8]; \
    }
  #define WRITE_V(b, vr)                                                          \
    {                                                                             \
      _Pragma("unroll")                                                           \
      for (int r = 0; r < 2; r++) {                                               \
        int hd0 = (w + r * 4) * 8;                                                \
        unsigned int u[4] = {vr[r].x, vr[r].y, vr[r].z, vr[r].w};                 \
        _Pragma("unroll")                                                         \
        for (int c2 = 0; c2 < 4; c2++) {                                          \
          Vt[b][(hd0 + 2 * c2    ) * 76 + vkey] = (unsigned short)(u[c2] & 0xffffu); \
          Vt[b][(hd0 + 2 * c2 + 1) * 76 + vkey] = (unsigned short)(u[c2] >> 16);  \
        }                                                                         \
      }                                                                           \
    }

  { // prologue: stage block 0
    STAGE_K(0, 0);
    uint4 vr0[2];
    LOAD_V(0, vr0);
    WRITE_V(0, vr0);
    __syncthreads();
  }

  for (int t = 0; t < 32; ++t) {
    const int cur = t & 1, o = cur ^ 1;
    const int k0 = t * 64;
    // prefetch next block while computing this one
    if (t < 31) STAGE_K(t + 1, o);
    uint4 vr[2];
    const bool vnext = (t < 31) && (t + 1 <= qt);
    if (vnext) LOAD_V(t + 1, vr);

    // S^T(64key x 16q) per wave
    f32x4 sf[4];
    #pragma unroll
    for (int kt = 0; kt < 4; kt++) sf[kt] = fz4();
    __builtin_amdgcn_s_setprio(1);
    #pragma unroll
    for (int kt = 0; kt < 4; kt++)
      #pragma unroll
      for (int kk = 0; kk < 2; kk++) {
        s16x8 kf = *(const s16x8*)&Ks[cur][(kt * 16 + l15) * 64 + (((kk * 4 + g) ^ (l15 & 7)) * 8)];
        sf[kt] = mfma32(kf, qf[kk], sf[kt]);
      }
    __builtin_amdgcn_s_setprio(0);

    // pre-mask block max for this lane's q, then across the 4 lane-groups
    float bm = -INFINITY;
    #pragma unroll
    for (int kt = 0; kt < 4; kt++)
      #pragma unroll
      for (int j = 0; j < 4; j++) bm = fmaxf(bm, sf[kt][j]);
    bm = fmaxf(bm, __shfl_xor(bm, 16));
    bm = fmaxf(bm, __shfl_xor(bm, 32));
    if (__any(bm > m)) {            // exact defer-max: skip rescale when max unchanged
      float mn  = fmaxf(m, bm);
      float fsc = __expf(m - mn);   // m = -inf initially -> 0
      m = mn;
      l *= fsc;
      float frow[4];
      #pragma unroll
      for (int j = 0; j < 4; j++) frow[j] = __shfl(fsc, 4 * g + j);
      #pragma unroll
      for (int d = 0; d < 4; d++)
        #pragma unroll
        for (int j = 0; j < 4; j++) outa[d][j] *= frow[j];
    }

    if (t <= qt) {
      s16x8 pfs[2];
      float rs = 0.f;
      #pragma unroll
      for (int kt2 = 0; kt2 < 2; kt2++) {
        #pragma unroll
        for (int j = 0; j < 4; j++) {
          int keyg = k0 + kt2 * 32 + 4 * g + j;
          float e = (keyg <= qrow) ? __expf(sf[2 * kt2][j] - m) : 0.f;
          rs += e;
          pfs[kt2][j] = (short)f2bf(e);
          float e2 = (keyg + 16 <= qrow) ? __expf(sf[2 * kt2 + 1][j] - m) : 0.f;
          rs += e2;
          pfs[kt2][4 + j] = (short)f2bf(e2);
        }
      }
      rs += __shfl_xor(rs, 16);
      rs += __shfl_xor(rs, 32);
      l += rs;
      __builtin_amdgcn_s_setprio(1);
      #pragma unroll
      for (int d = 0; d < 4; d++)
        #pragma unroll
        for (int kt2 = 0; kt2 < 2; kt2++) {
          s16x4 vlo = *(const s16x4*)&Vt[cur][(d * 16 + l15) * 76 + kt2 * 32 + 4 * g];
          s16x4 vhi = *(const s16x4*)&Vt[cur][(d * 16 + l15) * 76 + kt2 * 32 + 16 + 4 * g];
          s16x8 vv = {vlo[0], vlo[1], vlo[2], vlo[3], vhi[0], vhi[1], vhi[2], vhi[3]};
          outa[d] = mfma32(pfs[kt2], vv, outa[d]);
        }
      __builtin_amdgcn_s_setprio(0);
    }

    if (vnext) WRITE_V(o, vr);   // write-late: V regs land after compute
    __syncthreads();
  }
  #undef STAGE_K
  #undef LOAD_V
  #undef WRITE_V

  float inv = 1.f / (l + 1.f);   // quiet softmax +1
  float invr[4];
  #pragma unroll
  for (int j = 0; j < 4; j++) invr[j] = __shfl(inv, 4 * g + j);
  const int b = bh >> 4, h = bh & 15;
  #pragma unroll
  for (int d = 0; d < 4; d++)
    #pragma unroll
    for (int j = 0; j < 4; j++) {
      int row = q0 + w * 16 + 4 * g + j;
      int col = h * 64 + d * 16 + l15;
      AO[(size_t)(b * S_ + row) * D_ + col] = f2bf(outa[d][j] * invr[j]);
    }
}

extern "C" void kernel_launch(void* const* d_in, const int* in_sizes, int n_in,
                              void* d_out, int out_size, void* d_ws, size_t ws_size,
                              hipStream_t stream) {
  const float* q  = (const float*)d_in[0];
  const float* k  = (const float*)d_in[1];
  const float* v  = (const float*)d_in[2];
  const float* Wq = (const float*)d_in[3];
  const float* Wk = (const float*)d_in[4];
  const float* Wv = (const float*)d_in[5];
  const float* Wo = (const float*)d_in[6];

  unsigned short* ws  = (unsigned short*)d_ws;
  unsigned short* qb  = ws;                    // 4096x1024 bf16
  unsigned short* kb  = qb  + 4194304;
  unsigned short* vb  = kb  + 4194304;
  unsigned short* Wqb = vb  + 4194304;         // 1024x1024 bf16 x4
  unsigned short* Wkb = Wqb + 1048576;
  unsigned short* Wvb = Wkb + 1048576;
  unsigned short* Wob = Wvb + 1048576;
  unsigned short* Qh  = Wob + 1048576;         // (b,h,s,hd) bf16 x3
  unsigned short* Kh  = Qh  + 4194304;
  unsigned short* Vh  = Kh  + 4194304;
  unsigned short* AO  = Vh  + 4194304;         // attn out, (b*s, h*hd) bf16

  cvt_all<<<2048, 256, 0, stream>>>((const float4*)q, (const float4*)k, (const float4*)v,
                                    (const float4*)Wq, (const float4*)Wk, (const float4*)Wv,
                                    (const float4*)Wo,
                                    (uint2*)qb, (uint2*)kb, (uint2*)vb, (uint2*)Wqb,
                                    (uint2*)Wkb, (uint2*)Wvb, (uint2*)Wob);

  // fused QKV projections: 3 GEMMs x 256 blocks = 768 blocks (3/CU resident)
  gemm_bt<128, 0, 3><<<768, 256, 0, stream>>>(qb, kb, vb, Wqb, Wkb, Wvb,
                                              Qh, Kh, Vh, nullptr);

  attn_kernel<<<1024, 256, 0, stream>>>(Qh, Kh, Vh, AO);

  // output projection: 64x128 tiles -> 512 blocks (2/CU)
  gemm_bt<64, 1, 1><<<512, 256, 0, stream>>>(AO, nullptr, nullptr, Wob, nullptr, nullptr,
                                             nullptr, nullptr, nullptr, (float*)d_out);
}

// Round 5
// 223.851 us; speedup vs baseline: 1.4574x; 1.1289x over previous
//
#include <hip/hip_runtime.h>
#include <hip/hip_bf16.h>

#define B_  2
#define S_  2048
#define D_  1024
#define H_  16
#define HD_ 64

typedef __attribute__((ext_vector_type(4))) short s16x4;
typedef __attribute__((ext_vector_type(8))) short s16x8;
typedef __attribute__((ext_vector_type(4))) float f32x4;
typedef __attribute__((ext_vector_type(8))) __bf16 bf16x8;

__device__ __forceinline__ unsigned short f2bf(float x) {
  union { float f; unsigned int u; } un; un.f = x;
  unsigned int r = un.u + 0x7fffu + ((un.u >> 16) & 1u);  // RNE
  return (unsigned short)(r >> 16);
}

__device__ __forceinline__ f32x4 fz4() { f32x4 z = {0.f, 0.f, 0.f, 0.f}; return z; }

__device__ __forceinline__ f32x4 mfma32(s16x8 a, s16x8 b, f32x4 c) {
  return __builtin_amdgcn_mfma_f32_16x16x32_bf16(
      __builtin_bit_cast(bf16x8, a), __builtin_bit_cast(bf16x8, b), c, 0, 0, 0);
}

// async global->LDS, 16B per lane. Dest is wave-uniform base + lane*16 (HW adds lane).
__device__ __forceinline__ void gload16(void* lds_base, const void* gsrc) {
  __builtin_amdgcn_global_load_lds(
      (const __attribute__((address_space(1))) unsigned int*)gsrc,
      (__attribute__((address_space(3))) unsigned int*)lds_base, 16, 0, 0);
}

// ---------------- fp32 -> bf16 convert, ALL 7 tensors in one launch ----------------
__global__ __launch_bounds__(256) void cvt_all(const float4* __restrict__ q,
                                               const float4* __restrict__ k,
                                               const float4* __restrict__ v,
                                               const float4* __restrict__ wq,
                                               const float4* __restrict__ wk,
                                               const float4* __restrict__ wv,
                                               const float4* __restrict__ wo,
                                               uint2* __restrict__ oq, uint2* __restrict__ ok,
                                               uint2* __restrict__ ov, uint2* __restrict__ owq,
                                               uint2* __restrict__ owk, uint2* __restrict__ owv,
                                               uint2* __restrict__ owo) {
  int i = blockIdx.x * 256 + threadIdx.x;
  int st = gridDim.x * 256;
  for (; i < 4194304; i += st) {
    const float4* s; uint2* d; int off;
    if (i < 3145728) {
      int t = i >> 20; off = i & 1048575;
      s = (t == 0) ? q : (t == 1 ? k : v);
      d = (t == 0) ? oq : (t == 1 ? ok : ov);
    } else {
      int j = i - 3145728;
      int t = j >> 18; off = j & 262143;
      s = (t == 0) ? wq : (t == 1 ? wk : (t == 2 ? wv : wo));
      d = (t == 0) ? owq : (t == 1 ? owk : (t == 2 ? owv : owo));
    }
    float4 x = s[off];
    uint2 o;
    o.x = (unsigned)f2bf(x.x) | ((unsigned)f2bf(x.y) << 16);
    o.y = (unsigned)f2bf(x.z) | ((unsigned)f2bf(x.w) << 16);
    d[off] = o;
  }
}

// ---------------- GEMM  C[M,N] = A[M,K] @ W[N,K]^T
//   Tile BM x 128, BK=32, double-buffered LDS, 2-phase schedule (stage next
//   tile before compute, one barrier/iter). NG=3 fuses the QKV projections
//   into one launch (768 blocks = 3 panels/XCD) for 3-blocks/CU residency.
template<int BM, int MODE, int NG>
__global__ __launch_bounds__(256) void gemm_bt(
    const unsigned short* __restrict__ A0, const unsigned short* __restrict__ A1,
    const unsigned short* __restrict__ A2,
    const unsigned short* __restrict__ W0, const unsigned short* __restrict__ W1,
    const unsigned short* __restrict__ W2,
    unsigned short* __restrict__ ob0, unsigned short* __restrict__ ob1,
    unsigned short* __restrict__ ob2, float* __restrict__ of) {
  __shared__ unsigned short As[2][BM * 32];
  __shared__ unsigned short Bs[2][128 * 32];
  const int tid  = threadIdx.x;
  const int lane = tid & 63;
  const int w    = tid >> 6;
  const int l15  = lane & 15, g = lane >> 4;

  int m0, n0;
  const unsigned short *A, *W;
  unsigned short* obf;
  float scale = 1.0f;
  if (NG == 3) {
    int swz = ((int)blockIdx.x & 7) * 96 + ((int)blockIdx.x >> 3);
    int p  = swz >> 5;          // panel 0..23 (3 consecutive per XCD)
    int gi = p >> 3;            // which gemm
    n0 = (p & 7) * 128;
    m0 = (swz & 31) * 128;
    A   = gi == 0 ? A0 : (gi == 1 ? A1 : A2);
    W   = gi == 0 ? W0 : (gi == 1 ? W1 : W2);
    obf = gi == 0 ? ob0 : (gi == 1 ? ob1 : ob2);
    scale = (gi == 0) ? 0.125f : 1.0f;   // fold 1/sqrt(HD) into Q
  } else {
    int swz = ((int)blockIdx.x & 7) * 64 + ((int)blockIdx.x >> 3);
    m0 = (swz & 63) * BM;
    n0 = (swz >> 6) * 128;
    A = A0; W = W0; obf = ob0;
  }

  constexpr int MI  = (BM == 128) ? 4 : 2;
  const int wr = (w >> 1) * (MI * 16);
  const int wc = (w & 1) * 64;

  f32x4 acc[MI][4];
  #pragma unroll
  for (int i = 0; i < MI; i++)
    #pragma unroll
    for (int j = 0; j < 4; j++) acc[i][j] = fz4();

  // staging: rows are 32 shorts (64B) = 4 16B-chunks; T2 swizzle chunk^(row&3)
  // applied on the SOURCE address (LDS dest stays linear: gload_lds rule #21).
  const int srow = w * 16 + (lane >> 2);
  const int scol = ((lane & 3) ^ ((lane >> 2) & 3)) * 8;

  #define STAGE(buf, k0)                                                          \
    {                                                                             \
      _Pragma("unroll")                                                           \
      for (int i = 0; i < BM / 64; i++)                                           \
        gload16(&As[buf][(i * 64 + w * 16) * 32],                                 \
                &A[(size_t)(m0 + i * 64 + srow) * D_ + (k0) + scol]);             \
      _Pragma("unroll")                                                           \
      for (int i = 0; i < 2; i++)                                                 \
        gload16(&Bs[buf][(i * 64 + w * 16) * 32],                                 \
                &W[(size_t)(n0 + i * 64 + srow) * D_ + (k0) + scol]);             \
    }

  STAGE(0, 0);
  __syncthreads();
  int buf = 0;
  for (int t = 0; t < 32; ++t) {
    if (t < 31) STAGE(buf ^ 1, (t + 1) * 32);
    s16x8 af[MI], bfr[4];
    #pragma unroll
    for (int mi = 0; mi < MI; mi++)
      af[mi] = *(const s16x8*)&As[buf][(wr + mi * 16 + l15) * 32 + ((g ^ (l15 & 3)) * 8)];
    #pragma unroll
    for (int ni = 0; ni < 4; ni++)
      bfr[ni] = *(const s16x8*)&Bs[buf][(wc + ni * 16 + l15) * 32 + ((g ^ (l15 & 3)) * 8)];
    __builtin_amdgcn_s_setprio(1);
    #pragma unroll
    for (int mi = 0; mi < MI; mi++)
      #pragma unroll
      for (int ni = 0; ni < 4; ni++)
        acc[mi][ni] = mfma32(af[mi], bfr[ni], acc[mi][ni]);
    __builtin_amdgcn_s_setprio(0);
    __syncthreads();
    buf ^= 1;
  }
  #undef STAGE

  #pragma unroll
  for (int mi = 0; mi < MI; mi++)
    #pragma unroll
    for (int ni = 0; ni < 4; ni++)
      #pragma unroll
      for (int j = 0; j < 4; j++) {
        int r = m0 + wr + mi * 16 + 4 * g + j;   // output row (b*S+s)
        int c = n0 + wc + ni * 16 + l15;         // output col (h*HD+hd)
        float v = acc[mi][ni][j] * scale;
        if (MODE == 0) {
          int b = r >> 11, s = r & (S_ - 1), h = c >> 6, hd = c & 63;
          obf[(((size_t)(b * H_ + h)) * S_ + s) * HD_ + hd] = f2bf(v);
        } else {
          of[(size_t)r * D_ + c] = v;
        }
      }
}

// ---------------- Fused causal attention, quiet softmax (+1), PRE-MASK full-row max.
//   8 waves / 512 threads per block; waves 0-3 own q-tile i, waves 4-7 own q-tile
//   31-i (perfect balance: every block = 32 QK + 33 PV units), sharing K/V LDS.
//   Swapped QK^T (S^T = K @ Q^T); PV flipped (out^T = V^T P^T) so softmax stats
//   are lane-local (no rescale shuffles). Mask-split: only t==qt pays the cmp.
__global__ __launch_bounds__(512) void attn_kernel(const unsigned short* __restrict__ Qh,
                                                   const unsigned short* __restrict__ Kh,
                                                   const unsigned short* __restrict__ Vh,
                                                   unsigned short* __restrict__ AO) {
  __shared__ unsigned short Ks[2][64 * 64];   // [key][64] linear, chunk-swizzled content
  __shared__ unsigned short Vt[2][64 * 76];   // [hd][key], pad 76: conflict-free
  const int tid  = threadIdx.x;
  const int lane = tid & 63;
  const int w    = tid >> 6;       // 0..7
  const int wq   = w & 3;          // wave-in-group
  const int grp  = w >> 2;         // 0: tile A, 1: tile B
  const int l15  = lane & 15, g = lane >> 4;

  int swz = ((int)blockIdx.x & 7) * 64 + ((int)blockIdx.x >> 3);  // 512 blocks
  const int bh = swz >> 4;         // b*H + h
  const int pr = swz & 15;         // pair index
  const int qtA = pr, qtB = 31 - pr;
  const int myqt  = grp ? qtB : qtA;
  const int qtMax = qtB;           // qtB >= 16 > qtA
  const int q0 = myqt * 64;
  const unsigned short* Qb = Qh + (size_t)bh * S_ * HD_;
  const unsigned short* Kb = Kh + (size_t)bh * S_ * HD_;
  const unsigned short* Vb = Vh + (size_t)bh * S_ * HD_;

  const int qrow = q0 + wq * 16 + l15;  // this lane's q (column of S^T and of out^T)
  s16x8 qf[2];
  #pragma unroll
  for (int kk = 0; kk < 2; kk++)
    qf[kk] = *(const s16x8*)&Qb[(size_t)qrow * HD_ + kk * 32 + 8 * g];

  float m = -INFINITY, l = 0.f;     // stats for q = l15-row: lane-local
  f32x4 outa[4];                    // out^T: col=l15=q, rows 4g+j = hd within d*16
  #pragma unroll
  for (int d = 0; d < 4; d++) outa[d] = fz4();

  const int srow_l = lane >> 3;
  const int scol = ((lane & 7) ^ ((lane >> 3) & 7)) * 8;
  const int vkey = tid & 63;
  const int vhd0 = (tid >> 6) * 8;

  #define STAGE_K(kblk, b)                                                        \
    gload16(&Ks[b][(w * 8) * 64],                                                 \
            &Kb[(size_t)((kblk) * 64 + w * 8 + srow_l) * HD_ + scol]);
  #define LOAD_V(kblk, vr)                                                        \
    vr = *(const uint4*)&Vb[(size_t)((kblk) * 64 + vkey) * HD_ + vhd0];
  #define WRITE_V(b, vr)                                                          \
    {                                                                             \
      unsigned int u[4] = {vr.x, vr.y, vr.z, vr.w};                               \
      _Pragma("unroll")                                                           \
      for (int c2 = 0; c2 < 4; c2++) {                                            \
        Vt[b][(vhd0 + 2 * c2    ) * 76 + vkey] = (unsigned short)(u[c2] & 0xffffu); \
        Vt[b][(vhd0 + 2 * c2 + 1) * 76 + vkey] = (unsigned short)(u[c2] >> 16);   \
      }                                                                           \
    }

  { // prologue: stage block 0 (V block 0 always causal)
    STAGE_K(0, 0);
    uint4 vr0;
    LOAD_V(0, vr0);
    WRITE_V(0, vr0);
    __syncthreads();
  }

  for (int t = 0; t < 32; ++t) {
    const int cur = t & 1, nxt = cur ^ 1;
    const int k0 = t * 64;
    if (t < 31) STAGE_K(t + 1, nxt);
    uint4 vr;
    const bool vnext = (t < 31) && (t + 1 <= qtMax);
    if (vnext) LOAD_V(t + 1, vr);

    // S^T(64key x 16q) per wave
    f32x4 sf[4];
    #pragma unroll
    for (int kt = 0; kt < 4; kt++) sf[kt] = fz4();
    __builtin_amdgcn_s_setprio(1);
    #pragma unroll
    for (int kt = 0; kt < 4; kt++)
      #pragma unroll
      for (int kk = 0; kk < 2; kk++) {
        s16x8 kf = *(const s16x8*)&Ks[cur][(kt * 16 + l15) * 64 + (((kk * 4 + g) ^ (l15 & 7)) * 8)];
        sf[kt] = mfma32(kf, qf[kk], sf[kt]);
      }
    __builtin_amdgcn_s_setprio(0);

    // pre-mask block max for this lane's q, then across the 4 lane-groups
    float bm = -INFINITY;
    #pragma unroll
    for (int kt = 0; kt < 4; kt++)
      #pragma unroll
      for (int j = 0; j < 4; j++) bm = fmaxf(bm, sf[kt][j]);
    bm = fmaxf(bm, __shfl_xor(bm, 16));
    bm = fmaxf(bm, __shfl_xor(bm, 32));
    if (__any(bm > m)) {            // exact defer-max; lane-local rescale (out^T cols = own q)
      float mn  = fmaxf(m, bm);
      float fsc = __expf(m - mn);   // m = -inf initially -> 0
      m = mn;
      l *= fsc;
      #pragma unroll
      for (int d = 0; d < 4; d++)
        #pragma unroll
        for (int j = 0; j < 4; j++) outa[d][j] *= fsc;
    }

    if (t <= myqt) {
      s16x8 pfs[2];
      float rs = 0.f;
      if (t == myqt) {   // diagonal block: causal cmp per element
        #pragma unroll
        for (int kt2 = 0; kt2 < 2; kt2++)
          #pragma unroll
          for (int j = 0; j < 4; j++) {
            int keyg = k0 + kt2 * 32 + 4 * g + j;
            float e = (keyg <= qrow) ? __expf(sf[2 * kt2][j] - m) : 0.f;
            rs += e;
            pfs[kt2][j] = (short)f2bf(e);
            float e2 = (keyg + 16 <= qrow) ? __expf(sf[2 * kt2 + 1][j] - m) : 0.f;
            rs += e2;
            pfs[kt2][4 + j] = (short)f2bf(e2);
          }
      } else {           // strictly-below blocks: no mask
        #pragma unroll
        for (int kt2 = 0; kt2 < 2; kt2++)
          #pragma unroll
          for (int j = 0; j < 4; j++) {
            float e = __expf(sf[2 * kt2][j] - m);
            rs += e;
            pfs[kt2][j] = (short)f2bf(e);
            float e2 = __expf(sf[2 * kt2 + 1][j] - m);
            rs += e2;
            pfs[kt2][4 + j] = (short)f2bf(e2);
          }
      }
      rs += __shfl_xor(rs, 16);
      rs += __shfl_xor(rs, 32);
      l += rs;
      __builtin_amdgcn_s_setprio(1);
      #pragma unroll
      for (int d = 0; d < 4; d++)
        #pragma unroll
        for (int kt2 = 0; kt2 < 2; kt2++) {
          s16x4 vlo = *(const s16x4*)&Vt[cur][(d * 16 + l15) * 76 + kt2 * 32 + 4 * g];
          s16x4 vhi = *(const s16x4*)&Vt[cur][(d * 16 + l15) * 76 + kt2 * 32 + 16 + 4 * g];
          s16x8 vv = {vlo[0], vlo[1], vlo[2], vlo[3], vhi[0], vhi[1], vhi[2], vhi[3]};
          outa[d] = mfma32(vv, pfs[kt2], outa[d]);   // out^T += V^T * P^T
        }
      __builtin_amdgcn_s_setprio(0);
    }

    if (vnext) WRITE_V(nxt, vr);   // write-late: V regs land after compute
    __syncthreads();
  }
  #undef STAGE_K
  #undef LOAD_V
  #undef WRITE_V

  const float inv = 1.f / (l + 1.f);   // quiet softmax +1; lane-local
  const int b = bh >> 4, h = bh & 15;
  #pragma unroll
  for (int d = 0; d < 4; d++) {
    uint2 o;
    o.x = (unsigned)f2bf(outa[d][0] * inv) | ((unsigned)f2bf(outa[d][1] * inv) << 16);
    o.y = (unsigned)f2bf(outa[d][2] * inv) | ((unsigned)f2bf(outa[d][3] * inv) << 16);
    // row = this lane's q; cols = h*64 + d*16 + 4g + {0..3}
    *(uint2*)&AO[(size_t)(b * S_ + qrow) * D_ + h * 64 + d * 16 + 4 * g] = o;
  }
}

extern "C" void kernel_launch(void* const* d_in, const int* in_sizes, int n_in,
                              void* d_out, int out_size, void* d_ws, size_t ws_size,
                              hipStream_t stream) {
  const float* q  = (const float*)d_in[0];
  const float* k  = (const float*)d_in[1];
  const float* v  = (const float*)d_in[2];
  const float* Wq = (const float*)d_in[3];
  const float* Wk = (const float*)d_in[4];
  const float* Wv = (const float*)d_in[5];
  const float* Wo = (const float*)d_in[6];

  unsigned short* ws  = (unsigned short*)d_ws;
  unsigned short* qb  = ws;                    // 4096x1024 bf16
  unsigned short* kb  = qb  + 4194304;
  unsigned short* vb  = kb  + 4194304;
  unsigned short* Wqb = vb  + 4194304;         // 1024x1024 bf16 x4
  unsigned short* Wkb = Wqb + 1048576;
  unsigned short* Wvb = Wkb + 1048576;
  unsigned short* Wob = Wvb + 1048576;
  unsigned short* Qh  = Wob + 1048576;         // (b,h,s,hd) bf16 x3
  unsigned short* Kh  = Qh  + 4194304;
  unsigned short* Vh  = Kh  + 4194304;
  unsigned short* AO  = Vh  + 4194304;         // attn out, (b*s, h*hd) bf16

  cvt_all<<<2048, 256, 0, stream>>>((const float4*)q, (const float4*)k, (const float4*)v,
                                    (const float4*)Wq, (const float4*)Wk, (const float4*)Wv,
                                    (const float4*)Wo,
                                    (uint2*)qb, (uint2*)kb, (uint2*)vb, (uint2*)Wqb,
                                    (uint2*)Wkb, (uint2*)Wvb, (uint2*)Wob);

  // fused QKV projections: 3 GEMMs x 256 blocks = 768 blocks (3/CU resident)
  gemm_bt<128, 0, 3><<<768, 256, 0, stream>>>(qb, kb, vb, Wqb, Wkb, Wvb,
                                              Qh, Kh, Vh, nullptr);

  // paired q-tiles: 32 bh x 16 pairs = 512 blocks x 512 threads
  attn_kernel<<<512, 512, 0, stream>>>(Qh, Kh, Vh, AO);

  // output projection: 64x128 tiles -> 512 blocks (2/CU)
  gemm_bt<64, 1, 1><<<512, 256, 0, stream>>>(AO, nullptr, nullptr, Wob, nullptr, nullptr,
                                             nullptr, nullptr, nullptr, (float*)d_out);
}

// Round 6
// 219.664 us; speedup vs baseline: 1.4852x; 1.0191x over previous
//
#include <hip/hip_runtime.h>
#include <hip/hip_bf16.h>

#define B_  2
#define S_  2048
#define D_  1024
#define H_  16
#define HD_ 64

typedef __attribute__((ext_vector_type(4))) short s16x4;
typedef __attribute__((ext_vector_type(8))) short s16x8;
typedef __attribute__((ext_vector_type(4))) float f32x4;
typedef __attribute__((ext_vector_type(8))) __bf16 bf16x8;

__device__ __forceinline__ unsigned short f2bf(float x) {
  union { float f; unsigned int u; } un; un.f = x;
  unsigned int r = un.u + 0x7fffu + ((un.u >> 16) & 1u);  // RNE
  return (unsigned short)(r >> 16);
}

__device__ __forceinline__ f32x4 fz4() { f32x4 z = {0.f, 0.f, 0.f, 0.f}; return z; }

__device__ __forceinline__ f32x4 mfma32(s16x8 a, s16x8 b, f32x4 c) {
  return __builtin_amdgcn_mfma_f32_16x16x32_bf16(
      __builtin_bit_cast(bf16x8, a), __builtin_bit_cast(bf16x8, b), c, 0, 0, 0);
}

// async global->LDS, 16B per lane. Dest is wave-uniform base + lane*16 (HW adds lane).
__device__ __forceinline__ void gload16(void* lds_base, const void* gsrc) {
  __builtin_amdgcn_global_load_lds(
      (const __attribute__((address_space(1))) unsigned int*)gsrc,
      (__attribute__((address_space(3))) unsigned int*)lds_base, 16, 0, 0);
}

// ---------------- fp32 -> bf16 convert, ALL 7 tensors in one launch ----------------
__global__ __launch_bounds__(256) void cvt_all(const float4* __restrict__ q,
                                               const float4* __restrict__ k,
                                               const float4* __restrict__ v,
                                               const float4* __restrict__ wq,
                                               const float4* __restrict__ wk,
                                               const float4* __restrict__ wv,
                                               const float4* __restrict__ wo,
                                               uint2* __restrict__ oq, uint2* __restrict__ ok,
                                               uint2* __restrict__ ov, uint2* __restrict__ owq,
                                               uint2* __restrict__ owk, uint2* __restrict__ owv,
                                               uint2* __restrict__ owo) {
  int i = blockIdx.x * 256 + threadIdx.x;
  int st = gridDim.x * 256;
  for (; i < 4194304; i += st) {
    const float4* s; uint2* d; int off;
    if (i < 3145728) {
      int t = i >> 20; off = i & 1048575;
      s = (t == 0) ? q : (t == 1 ? k : v);
      d = (t == 0) ? oq : (t == 1 ? ok : ov);
    } else {
      int j = i - 3145728;
      int t = j >> 18; off = j & 262143;
      s = (t == 0) ? wq : (t == 1 ? wk : (t == 2 ? wv : wo));
      d = (t == 0) ? owq : (t == 1 ? owk : (t == 2 ? owv : owo));
    }
    float4 x = s[off];
    uint2 o;
    o.x = (unsigned)f2bf(x.x) | ((unsigned)f2bf(x.y) << 16);
    o.y = (unsigned)f2bf(x.z) | ((unsigned)f2bf(x.w) << 16);
    d[off] = o;
  }
}

// ---------------- QKV GEMM: 256x256 tile, BK=64, 8 waves, 8-phase-style schedule
//   with counted vmcnt (T3+T4), double-buffered 128 KiB LDS, source-side XOR swizzle.
//   Fused over the 3 projections: M = 3*4096 logical rows.
__global__ __launch_bounds__(512, 2) void qkv256(
    const unsigned short* __restrict__ A0, const unsigned short* __restrict__ A1,
    const unsigned short* __restrict__ A2,
    const unsigned short* __restrict__ W0, const unsigned short* __restrict__ W1,
    const unsigned short* __restrict__ W2,
    unsigned short* __restrict__ ob0, unsigned short* __restrict__ ob1,
    unsigned short* __restrict__ ob2) {
  __shared__ unsigned short As[2][16384];   // 256 rows x 64 (128B rows), chunk-swizzled
  __shared__ unsigned short Bs[2][16384];
  const int tid  = threadIdx.x;
  const int lane = tid & 63;
  const int w    = tid >> 6;        // 0..7
  const int l15  = lane & 15, g = lane >> 4;
  const int wm   = w >> 2;          // 0..1  (M-half of the 256-tile)
  const int wn   = w & 3;           // 0..3  (N-quarter)

  // 192 blocks: bijective XCD swizzle (192 % 8 == 0); consecutive swz share N-panel.
  int swz = ((int)blockIdx.x & 7) * 24 + ((int)blockIdx.x >> 3);
  const int nt = swz / 48;          // 0..3
  const int mt = swz % 48;          // 0..47
  const int gi = mt >> 4;           // which projection
  const int m0 = (mt & 15) * 256;
  const int n0 = nt * 256;
  const unsigned short* A = gi == 0 ? A0 : (gi == 1 ? A1 : A2);
  const unsigned short* W = gi == 0 ? W0 : (gi == 1 ? W1 : W2);
  unsigned short* obf     = gi == 0 ? ob0 : (gi == 1 ? ob1 : ob2);
  const float scale = (gi == 0) ? 0.125f : 1.0f;

  f32x4 acc[8][4];
  #pragma unroll
  for (int i = 0; i < 8; i++)
    #pragma unroll
    for (int j = 0; j < 4; j++) acc[i][j] = fz4();

  // staging: instr-group i covers rows i*64 + w*8 + (lane>>3); 8 chunks of 16B per row,
  // content chunk c holds source chunk c ^ (row&7)  (swizzle on the SOURCE, rule #21).
  const int srow_i = w * 8 + (lane >> 3);
  const int scol   = ((lane & 7) ^ ((lane >> 3) & 7)) * 8;

  #define SG_A(nb, i, kt) gload16(&As[nb][((i) * 512 + w * 64) * 8],                     \
      &A[(size_t)(m0 + (i) * 64 + srow_i) * D_ + (kt) * 64 + scol])
  #define SG_B(nb, i, kt) gload16(&Bs[nb][((i) * 512 + w * 64) * 8],                     \
      &W[(size_t)(n0 + (i) * 64 + srow_i) * D_ + (kt) * 64 + scol])

  #define RD_A(dst, mq, bufi)                                                            \
    _Pragma("unroll") for (int fi = 0; fi < 4; fi++)                                     \
      _Pragma("unroll") for (int kk = 0; kk < 2; kk++)                                   \
        dst[fi][kk] = *(const s16x8*)&As[bufi][(wm * 128 + (mq) * 64 + fi * 16 + l15) * 64 \
                                              + (((kk * 4 + g) ^ (l15 & 7)) * 8)];
  #define RD_B(dst, nq, bufi)                                                            \
    _Pragma("unroll") for (int fj = 0; fj < 2; fj++)                                     \
      _Pragma("unroll") for (int kk = 0; kk < 2; kk++)                                   \
        dst[fj][kk] = *(const s16x8*)&Bs[bufi][(wn * 64 + (nq) * 32 + fj * 16 + l15) * 64  \
                                              + (((kk * 4 + g) ^ (l15 & 7)) * 8)];
  #define MM(mq, nq, av, bv)                                                             \
    _Pragma("unroll") for (int fi = 0; fi < 4; fi++)                                     \
      _Pragma("unroll") for (int fj = 0; fj < 2; fj++)                                   \
        _Pragma("unroll") for (int kk = 0; kk < 2; kk++)                                 \
          acc[(mq) * 4 + fi][(nq) * 2 + fj] =                                            \
              mfma32(av[fi][kk], bv[fj][kk], acc[(mq) * 4 + fi][(nq) * 2 + fj]);

  // prologue: stage K-tile 0; order A0,A2,B0..B3 (needed at P1) then A1,A3 (needed at P3)
  SG_A(0, 0, 0); SG_A(0, 2, 0);
  SG_B(0, 0, 0); SG_B(0, 1, 0); SG_B(0, 2, 0); SG_B(0, 3, 0);
  SG_A(0, 1, 0); SG_A(0, 3, 0);

  s16x8 a[4][2], b0[2][2], b1[2][2];
  for (int t = 0; t < 16; ++t) {
    const int buf = t & 1, nb = buf ^ 1;
    const int tn = (t + 1) & 15;   // wrap: dummy re-stage at t=15 keeps vmcnt counts uniform
    // ---- P1: quadrant (m0,n0). Needs A-even + all B of tile t.
    asm volatile("s_waitcnt vmcnt(2)" ::: "memory");
    __builtin_amdgcn_s_barrier();
    RD_A(a, 0, buf);
    RD_B(b0, 0, buf);
    SG_A(nb, 0, tn); SG_A(nb, 2, tn);
    asm volatile("s_waitcnt lgkmcnt(0)" ::: "memory");
    __builtin_amdgcn_s_setprio(1);
    MM(0, 0, a, b0);
    __builtin_amdgcn_s_setprio(0);
    __builtin_amdgcn_s_barrier();
    // ---- P2: quadrant (m0,n1). Reuses A; reads B-n1.
    RD_B(b1, 1, buf);
    SG_B(nb, 0, tn); SG_B(nb, 1, tn); SG_B(nb, 2, tn); SG_B(nb, 3, tn);
    asm volatile("s_waitcnt lgkmcnt(0)" ::: "memory");
    __builtin_amdgcn_s_setprio(1);
    MM(0, 1, a, b1);
    __builtin_amdgcn_s_setprio(0);
    __builtin_amdgcn_s_barrier();
    // ---- P3: quadrant (m1,n1). Needs A-odd of tile t.
    asm volatile("s_waitcnt vmcnt(6)" ::: "memory");
    __builtin_amdgcn_s_barrier();
    RD_A(a, 1, buf);
    SG_A(nb, 1, tn); SG_A(nb, 3, tn);
    asm volatile("s_waitcnt lgkmcnt(0)" ::: "memory");
    __builtin_amdgcn_s_setprio(1);
    MM(1, 1, a, b1);
    __builtin_amdgcn_s_setprio(0);
    __builtin_amdgcn_s_barrier();
    // ---- P4: quadrant (m1,n0). Re-reads B-n0.
    RD_B(b0, 0, buf);
    asm volatile("s_waitcnt lgkmcnt(0)" ::: "memory");
    __builtin_amdgcn_s_setprio(1);
    MM(1, 0, a, b0);
    __builtin_amdgcn_s_setprio(0);
    __builtin_amdgcn_s_barrier();
  }
  asm volatile("s_waitcnt vmcnt(0)" ::: "memory");  // drain dummy stage before exit

  #undef SG_A
  #undef SG_B
  #undef RD_A
  #undef RD_B
  #undef MM

  #pragma unroll
  for (int mi = 0; mi < 8; mi++)
    #pragma unroll
    for (int ni = 0; ni < 4; ni++)
      #pragma unroll
      for (int j = 0; j < 4; j++) {
        int r = m0 + wm * 128 + mi * 16 + 4 * g + j;   // row within this gemm (b*S+s)
        int c = n0 + wn * 64 + ni * 16 + l15;          // col (h*HD+hd)
        float v = acc[mi][ni][j] * scale;
        int b = r >> 11, s = r & (S_ - 1), h = c >> 6, hd = c & 63;
        obf[(((size_t)(b * H_ + h)) * S_ + s) * HD_ + hd] = f2bf(v);
      }
}

// ---------------- Wo GEMM  C[M,N] = A[M,K] @ W[N,K]^T  (64x128 tile, BK=32 dbuf) ------
__global__ __launch_bounds__(256) void gemm_wo(const unsigned short* __restrict__ A,
                                               const unsigned short* __restrict__ W,
                                               float* __restrict__ of) {
  __shared__ unsigned short As[2][64 * 32];
  __shared__ unsigned short Bs[2][128 * 32];
  const int tid  = threadIdx.x;
  const int lane = tid & 63;
  const int w    = tid >> 6;
  const int l15  = lane & 15, g = lane >> 4;

  int swz = ((int)blockIdx.x & 7) * 64 + ((int)blockIdx.x >> 3);
  const int m0 = (swz & 63) * 64;
  const int n0 = (swz >> 6) * 128;
  const int wr = (w >> 1) * 32, wc = (w & 1) * 64;

  f32x4 acc[2][4];
  #pragma unroll
  for (int i = 0; i < 2; i++)
    #pragma unroll
    for (int j = 0; j < 4; j++) acc[i][j] = fz4();

  const int srow = w * 16 + (lane >> 2);
  const int scol = ((lane & 3) ^ ((lane >> 2) & 3)) * 8;

  #define STAGE(buf, k0)                                                          \
    {                                                                             \
      gload16(&As[buf][(w * 16) * 32],                                            \
              &A[(size_t)(m0 + srow) * D_ + (k0) + scol]);                        \
      _Pragma("unroll")                                                           \
      for (int i = 0; i < 2; i++)                                                 \
        gload16(&Bs[buf][(i * 64 + w * 16) * 32],                                 \
                &W[(size_t)(n0 + i * 64 + srow) * D_ + (k0) + scol]);             \
    }

  STAGE(0, 0);
  __syncthreads();
  int buf = 0;
  for (int t = 0; t < 32; ++t) {
    if (t < 31) STAGE(buf ^ 1, (t + 1) * 32);
    s16x8 af[2], bfr[4];
    #pragma unroll
    for (int mi = 0; mi < 2; mi++)
      af[mi] = *(const s16x8*)&As[buf][(wr + mi * 16 + l15) * 32 + ((g ^ (l15 & 3)) * 8)];
    #pragma unroll
    for (int ni = 0; ni < 4; ni++)
      bfr[ni] = *(const s16x8*)&Bs[buf][(wc + ni * 16 + l15) * 32 + ((g ^ (l15 & 3)) * 8)];
    __builtin_amdgcn_s_setprio(1);
    #pragma unroll
    for (int mi = 0; mi < 2; mi++)
      #pragma unroll
      for (int ni = 0; ni < 4; ni++)
        acc[mi][ni] = mfma32(af[mi], bfr[ni], acc[mi][ni]);
    __builtin_amdgcn_s_setprio(0);
    __syncthreads();
    buf ^= 1;
  }
  #undef STAGE

  #pragma unroll
  for (int mi = 0; mi < 2; mi++)
    #pragma unroll
    for (int ni = 0; ni < 4; ni++)
      #pragma unroll
      for (int j = 0; j < 4; j++) {
        int r = m0 + wr + mi * 16 + 4 * g + j;
        int c = n0 + wc + ni * 16 + l15;
        of[(size_t)r * D_ + c] = acc[mi][ni][j];
      }
}

// ---------------- Fused causal attention, quiet softmax (+1), PRE-MASK full-row max.
//   8 waves / 512 threads per block; waves 0-3 own q-tile i, waves 4-7 own q-tile
//   31-i (perfect balance), sharing K/V LDS. Swapped QK^T; PV flipped (out^T = V^T P^T)
//   so softmax stats are lane-local. Mask-split: only t==qt pays the cmp.
__global__ __launch_bounds__(512) void attn_kernel(const unsigned short* __restrict__ Qh,
                                                   const unsigned short* __restrict__ Kh,
                                                   const unsigned short* __restrict__ Vh,
                                                   unsigned short* __restrict__ AO) {
  __shared__ unsigned short Ks[2][64 * 64];   // [key][64] linear, chunk-swizzled content
  __shared__ unsigned short Vt[2][64 * 76];   // [hd][key], pad 76: conflict-free
  const int tid  = threadIdx.x;
  const int lane = tid & 63;
  const int w    = tid >> 6;       // 0..7
  const int wq   = w & 3;          // wave-in-group
  const int grp  = w >> 2;         // 0: tile A, 1: tile B
  const int l15  = lane & 15, g = lane >> 4;

  int swz = ((int)blockIdx.x & 7) * 64 + ((int)blockIdx.x >> 3);  // 512 blocks
  const int bh = swz >> 4;         // b*H + h
  const int pr = swz & 15;         // pair index
  const int qtA = pr, qtB = 31 - pr;
  const int myqt  = grp ? qtB : qtA;
  const int qtMax = qtB;           // qtB >= 16 > qtA
  const int q0 = myqt * 64;
  const unsigned short* Qb = Qh + (size_t)bh * S_ * HD_;
  const unsigned short* Kb = Kh + (size_t)bh * S_ * HD_;
  const unsigned short* Vb = Vh + (size_t)bh * S_ * HD_;

  const int qrow = q0 + wq * 16 + l15;  // this lane's q (column of S^T and of out^T)
  s16x8 qf[2];
  #pragma unroll
  for (int kk = 0; kk < 2; kk++)
    qf[kk] = *(const s16x8*)&Qb[(size_t)qrow * HD_ + kk * 32 + 8 * g];

  float m = -INFINITY, l = 0.f;     // stats for q = l15-row: lane-local
  f32x4 outa[4];                    // out^T: col=l15=q, rows 4g+j = hd within d*16
  #pragma unroll
  for (int d = 0; d < 4; d++) outa[d] = fz4();

  const int srow_l = lane >> 3;
  const int scol = ((lane & 7) ^ ((lane >> 3) & 7)) * 8;
  const int vkey = tid & 63;
  const int vhd0 = (tid >> 6) * 8;

  #define STAGE_K(kblk, b)                                                        \
    gload16(&Ks[b][(w * 8) * 64],                                                 \
            &Kb[(size_t)((kblk) * 64 + w * 8 + srow_l) * HD_ + scol]);
  #define LOAD_V(kblk, vr)                                                        \
    vr = *(const uint4*)&Vb[(size_t)((kblk) * 64 + vkey) * HD_ + vhd0];
  #define WRITE_V(b, vr)                                                          \
    {                                                                             \
      unsigned int u[4] = {vr.x, vr.y, vr.z, vr.w};                               \
      _Pragma("unroll")                                                           \
      for (int c2 = 0; c2 < 4; c2++) {                                            \
        Vt[b][(vhd0 + 2 * c2    ) * 76 + vkey] = (unsigned short)(u[c2] & 0xffffu); \
        Vt[b][(vhd0 + 2 * c2 + 1) * 76 + vkey] = (unsigned short)(u[c2] >> 16);   \
      }                                                                           \
    }

  { // prologue: stage block 0 (V block 0 always causal)
    STAGE_K(0, 0);
    uint4 vr0;
    LOAD_V(0, vr0);
    WRITE_V(0, vr0);
    __syncthreads();
  }

  for (int t = 0; t < 32; ++t) {
    const int cur = t & 1, nxt = cur ^ 1;
    const int k0 = t * 64;
    if (t < 31) STAGE_K(t + 1, nxt);
    uint4 vr;
    const bool vnext = (t < 31) && (t + 1 <= qtMax);
    if (vnext) LOAD_V(t + 1, vr);

    // S^T(64key x 16q) per wave
    f32x4 sf[4];
    #pragma unroll
    for (int kt = 0; kt < 4; kt++) sf[kt] = fz4();
    __builtin_amdgcn_s_setprio(1);
    #pragma unroll
    for (int kt = 0; kt < 4; kt++)
      #pragma unroll
      for (int kk = 0; kk < 2; kk++) {
        s16x8 kf = *(const s16x8*)&Ks[cur][(kt * 16 + l15) * 64 + (((kk * 4 + g) ^ (l15 & 7)) * 8)];
        sf[kt] = mfma32(kf, qf[kk], sf[kt]);
      }
    __builtin_amdgcn_s_setprio(0);

    // pre-mask block max for this lane's q, then across the 4 lane-groups
    float bm = -INFINITY;
    #pragma unroll
    for (int kt = 0; kt < 4; kt++)
      #pragma unroll
      for (int j = 0; j < 4; j++) bm = fmaxf(bm, sf[kt][j]);
    bm = fmaxf(bm, __shfl_xor(bm, 16));
    bm = fmaxf(bm, __shfl_xor(bm, 32));
    if (__any(bm > m)) {            // exact defer-max; lane-local rescale (out^T cols = own q)
      float mn  = fmaxf(m, bm);
      float fsc = __expf(m - mn);   // m = -inf initially -> 0
      m = mn;
      l *= fsc;
      #pragma unroll
      for (int d = 0; d < 4; d++)
        #pragma unroll
        for (int j = 0; j < 4; j++) outa[d][j] *= fsc;
    }

    if (t <= myqt) {
      s16x8 pfs[2];
      float rs = 0.f;
      if (t == myqt) {   // diagonal block: causal cmp per element
        #pragma unroll
        for (int kt2 = 0; kt2 < 2; kt2++)
          #pragma unroll
          for (int j = 0; j < 4; j++) {
            int keyg = k0 + kt2 * 32 + 4 * g + j;
            float e = (keyg <= qrow) ? __expf(sf[2 * kt2][j] - m) : 0.f;
            rs += e;
            pfs[kt2][j] = (short)f2bf(e);
            float e2 = (keyg + 16 <= qrow) ? __expf(sf[2 * kt2 + 1][j] - m) : 0.f;
            rs += e2;
            pfs[kt2][4 + j] = (short)f2bf(e2);
          }
      } else {           // strictly-below blocks: no mask
        #pragma unroll
        for (int kt2 = 0; kt2 < 2; kt2++)
          #pragma unroll
          for (int j = 0; j < 4; j++) {
            float e = __expf(sf[2 * kt2][j] - m);
            rs += e;
            pfs[kt2][j] = (short)f2bf(e);
            float e2 = __expf(sf[2 * kt2 + 1][j] - m);
            rs += e2;
            pfs[kt2][4 + j] = (short)f2bf(e2);
          }
      }
      rs += __shfl_xor(rs, 16);
      rs += __shfl_xor(rs, 32);
      l += rs;
      __builtin_amdgcn_s_setprio(1);
      #pragma unroll
      for (int d = 0; d < 4; d++)
        #pragma unroll
        for (int kt2 = 0; kt2 < 2; kt2++) {
          s16x4 vlo = *(const s16x4*)&Vt[cur][(d * 16 + l15) * 76 + kt2 * 32 + 4 * g];
          s16x4 vhi = *(const s16x4*)&Vt[cur][(d * 16 + l15) * 76 + kt2 * 32 + 16 + 4 * g];
          s16x8 vv = {vlo[0], vlo[1], vlo[2], vlo[3], vhi[0], vhi[1], vhi[2], vhi[3]};
          outa[d] = mfma32(vv, pfs[kt2], outa[d]);   // out^T += V^T * P^T
        }
      __builtin_amdgcn_s_setprio(0);
    }

    if (vnext) WRITE_V(nxt, vr);   // write-late: V regs land after compute
    __syncthreads();
  }
  #undef STAGE_K
  #undef LOAD_V
  #undef WRITE_V

  const float inv = 1.f / (l + 1.f);   // quiet softmax +1; lane-local
  const int b = bh >> 4, h = bh & 15;
  #pragma unroll
  for (int d = 0; d < 4; d++) {
    uint2 o;
    o.x = (unsigned)f2bf(outa[d][0] * inv) | ((unsigned)f2bf(outa[d][1] * inv) << 16);
    o.y = (unsigned)f2bf(outa[d][2] * inv) | ((unsigned)f2bf(outa[d][3] * inv) << 16);
    *(uint2*)&AO[(size_t)(b * S_ + qrow) * D_ + h * 64 + d * 16 + 4 * g] = o;
  }
}

extern "C" void kernel_launch(void* const* d_in, const int* in_sizes, int n_in,
                              void* d_out, int out_size, void* d_ws, size_t ws_size,
                              hipStream_t stream) {
  const float* q  = (const float*)d_in[0];
  const float* k  = (const float*)d_in[1];
  const float* v  = (const float*)d_in[2];
  const float* Wq = (const float*)d_in[3];
  const float* Wk = (const float*)d_in[4];
  const float* Wv = (const float*)d_in[5];
  const float* Wo = (const float*)d_in[6];

  unsigned short* ws  = (unsigned short*)d_ws;
  unsigned short* qb  = ws;                    // 4096x1024 bf16
  unsigned short* kb  = qb  + 4194304;
  unsigned short* vb  = kb  + 4194304;
  unsigned short* Wqb = vb  + 4194304;         // 1024x1024 bf16 x4
  unsigned short* Wkb = Wqb + 1048576;
  unsigned short* Wvb = Wkb + 1048576;
  unsigned short* Wob = Wvb + 1048576;
  unsigned short* Qh  = Wob + 1048576;         // (b,h,s,hd) bf16 x3
  unsigned short* Kh  = Qh  + 4194304;
  unsigned short* Vh  = Kh  + 4194304;
  unsigned short* AO  = Vh  + 4194304;         // attn out, (b*s, h*hd) bf16

  cvt_all<<<2048, 256, 0, stream>>>((const float4*)q, (const float4*)k, (const float4*)v,
                                    (const float4*)Wq, (const float4*)Wk, (const float4*)Wv,
                                    (const float4*)Wo,
                                    (uint2*)qb, (uint2*)kb, (uint2*)vb, (uint2*)Wqb,
                                    (uint2*)Wkb, (uint2*)Wvb, (uint2*)Wob);

  // fused QKV projections: 256^2 tiles, 8-phase counted-vmcnt schedule, 192 blocks
  qkv256<<<192, 512, 0, stream>>>(qb, kb, vb, Wqb, Wkb, Wvb, Qh, Kh, Vh);

  // paired q-tiles: 32 bh x 16 pairs = 512 blocks x 512 threads
  attn_kernel<<<512, 512, 0, stream>>>(Qh, Kh, Vh, AO);

  // output projection: 64x128 tiles -> 512 blocks (2/CU)
  gemm_wo<<<512, 256, 0, stream>>>(AO, Wob, (float*)d_out);
}